// Round 9
// baseline (209.437 us; speedup 1.0000x reference)
//
#include <hip/hip_runtime.h>

#define B_DIM 8192
#define C_DIM 10000
#define C4    2500      // C_DIM / 4 (float4 groups)
#define NT    10        // column tiles of 256 float4 = 1024 columns
#define TILE4 256
#define NCHUNK 128      // row chunks -> grid 10x128 = 1280 blocks = 5/CU exact
#define ROWCHUNK (B_DIM / NCHUNK)   // 64
#define WROWS (ROWCHUNK / 4)        // 16 contiguous rows per wave
#define NCB   157       // column blocks in fin2 (ceil(2500/16))

typedef float v4f __attribute__((ext_vector_type(4)));

// Deterministic single-block bitonic sort of (target<<13 | rowidx) keys.
// Fixed comparison network -> same permutation every call.
__global__ __launch_bounds__(1024) void sort_kernel(
    const int* __restrict__ target, unsigned* __restrict__ perm) {
    __shared__ unsigned key[B_DIM];   // 32 KB
    const int tid = threadIdx.x;
    for (int i = tid; i < B_DIM; i += 1024)
        key[i] = ((unsigned)target[i] << 13) | (unsigned)i;
    __syncthreads();
    for (int k = 2; k <= B_DIM; k <<= 1) {
        for (int j = k >> 1; j > 0; j >>= 1) {
            for (int i = tid; i < B_DIM; i += 1024) {
                const int ixj = i ^ j;
                if (ixj > i) {
                    const unsigned a = key[i], b = key[ixj];
                    const bool asc = ((i & k) == 0);
                    if ((a > b) == asc) { key[i] = b; key[ixj] = a; }
                }
            }
            __syncthreads();
        }
    }
    for (int i = tid; i < B_DIM; i += 1024)
        perm[i] = key[i] & (B_DIM - 1);
}

// Fused main pass over target-sorted rows. Grid (NT, NCHUNK), block 256.
// Each wave takes 16 CONTIGUOUS sorted rows; consecutive rows with the same
// target reuse the D registers (skip 4 loads) - ~2600 of 8192 rows skip.
__global__ __launch_bounds__(256) void fused_main(
    const v4f* __restrict__ x4, const v4f* __restrict__ dm4,
    const int* __restrict__ target, const unsigned* __restrict__ perm,
    v4f* __restrict__ colExpPart, v4f* __restrict__ colDPart,
    float* __restrict__ rowPartExp, float* __restrict__ rowPartDx,
    float* __restrict__ xt) {
    const int tile  = blockIdx.x;
    const int chunk = blockIdx.y;
    const int tid   = threadIdx.x;
    const int lane  = tid & 63;
    const int wave  = tid >> 6;
    const int base4 = tile * TILE4;
    const int row0  = chunk * ROWCHUNK;

    __shared__ int s_sr[ROWCHUNK];
    __shared__ int s_t[ROWCHUNK];
    __shared__ v4f sE[TILE4];
    __shared__ v4f sD[TILE4];

    for (int r = tid; r < ROWCHUNK; r += 256) {
        const int sr = (int)perm[row0 + r];
        s_sr[r] = sr;
        s_t[r]  = target[sr];
    }
    __syncthreads();

    int  col4[4];
    bool valid[4];
    v4f accE[4], accD[4], dv[4];
#pragma unroll
    for (int it = 0; it < 4; ++it) {
        col4[it]  = base4 + it * 64 + lane;
        valid[it] = col4[it] < C4;
        accE[it] = (v4f){0.f, 0.f, 0.f, 0.f};
        accD[it] = (v4f){0.f, 0.f, 0.f, 0.f};
        dv[it]   = (v4f){0.f, 0.f, 0.f, 0.f};
    }

    int prev_t = -1;
    for (int rr = 0; rr < WROWS; ++rr) {
        const int r    = wave * WROWS + rr;
        const int srow = s_sr[r];
        const int t    = s_t[r];
        const v4f* xrow = x4 + (size_t)srow * C4;
        if (t != prev_t) {           // wave-uniform (scalar branch)
            const v4f* drow = dm4 + (size_t)t * C4;
#pragma unroll
            for (int it = 0; it < 4; ++it)
                if (valid[it]) dv[it] = drow[col4[it]];
            prev_t = t;
        }
        const int tq = t >> 2, tl = t & 3;
        float rowE = 0.f, rowDx = 0.f;
#pragma unroll
        for (int it = 0; it < 4; ++it) {
            if (!valid[it]) continue;
            // x streamed once: non-temporal keeps L2/L3 reserved for D rows.
            v4f xv = __builtin_nontemporal_load(&xrow[col4[it]]);
            float ex = __expf(xv.x), ey = __expf(xv.y),
                  ez = __expf(xv.z), ew = __expf(xv.w);
            accE[it].x += ex; accE[it].y += ey;
            accE[it].z += ez; accE[it].w += ew;
            rowE += (ex + ey) + (ez + ew);
            accD[it] += dv[it];
            rowDx += dv[it].x * xv.x + dv[it].y * xv.y
                   + dv[it].z * xv.z + dv[it].w * xv.w;
            if (col4[it] == tq) {
                float v = (tl == 0) ? xv.x : (tl == 1) ? xv.y
                        : (tl == 2) ? xv.z : xv.w;
                xt[srow] = v;
            }
        }
#pragma unroll
        for (int off = 32; off > 0; off >>= 1) {
            rowE  += __shfl_down(rowE, off, 64);
            rowDx += __shfl_down(rowDx, off, 64);
        }
        if (lane == 0) {
            rowPartExp[(size_t)tile * B_DIM + srow] = rowE;
            rowPartDx [(size_t)tile * B_DIM + srow] = rowDx;
        }
    }

    // Combine column partials across the 4 waves via LDS (deterministic).
    if (wave == 0) {
#pragma unroll
        for (int it = 0; it < 4; ++it) {
            sE[it * 64 + lane] = accE[it];
            sD[it * 64 + lane] = accD[it];
        }
    }
    __syncthreads();
    for (int w = 1; w < 4; ++w) {
        if (wave == w) {
#pragma unroll
            for (int it = 0; it < 4; ++it) {
                sE[it * 64 + lane] += accE[it];
                sD[it * 64 + lane] += accD[it];
            }
        }
        __syncthreads();
    }
    const int colg = base4 + tid;
    if (colg < C4) {
        colExpPart[(size_t)chunk * C4 + colg] = sE[tid];
        colDPart [(size_t)chunk * C4 + colg] = sD[tid];
    }
}

// Single merged finalize. Grid NCB+32 = 189 blocks x 256. (round-6 identical)
__global__ __launch_bounds__(256) void fin2_kernel(
    const v4f* __restrict__ colExpPart, const v4f* __restrict__ colDPart,
    const float* __restrict__ rowPartExp, const float* __restrict__ rowPartDx,
    const float* __restrict__ xt, double* __restrict__ partials) {
    const int b   = blockIdx.x;
    const int tid = threadIdx.x;
    __shared__ double sred[256];

    if (b < NCB) {
        const int cl   = tid & 15;
        const int q    = tid >> 4;           // 0..15
        const int col4 = b * 16 + cl;
        v4f se = {0.f, 0.f, 0.f, 0.f};
        v4f sd = {0.f, 0.f, 0.f, 0.f};
        if (col4 < C4) {
            for (int c = q; c < NCHUNK; c += 16) {
                se += __builtin_nontemporal_load(&colExpPart[(size_t)c * C4 + col4]);
                sd += __builtin_nontemporal_load(&colDPart [(size_t)c * C4 + col4]);
            }
        }
        __shared__ v4f lE[256], lD[256];
        lE[tid] = se; lD[tid] = sd;
        __syncthreads();
        for (int s = 8; s > 0; s >>= 1) {     // tree over q
            if (q < s) { lE[tid] += lE[tid + s * 16]; lD[tid] += lD[tid + s * 16]; }
            __syncthreads();
        }
        double mine = 0.0;
        if (q == 0 && col4 < C4) {
            v4f e = lE[tid];
            v4f d = lD[tid];
            mine = (double)d.x * (double)__logf(e.x)
                 + (double)d.y * (double)__logf(e.y)
                 + (double)d.z * (double)__logf(e.z)
                 + (double)d.w * (double)__logf(e.w);
        }
        sred[tid] = mine;
        __syncthreads();
        for (int s = 128; s > 0; s >>= 1) {
            if (tid < s) sred[tid] += sred[tid + s];
            __syncthreads();
        }
        if (tid == 0) partials[b] = sred[0];
    } else {
        const int s = b - NCB;
        const int i = s * 256 + tid;          // < 8192 exactly
        float re = 0.f, rdx = 0.f;
#pragma unroll
        for (int t = 0; t < NT; ++t) {
            re  += rowPartExp[(size_t)t * B_DIM + i];
            rdx += rowPartDx [(size_t)t * B_DIM + i];
        }
        double mine  = (double)(__logf(re) - xt[i]);
        double mine2 = (double)rdx;
        __shared__ double sred2[256];
        sred[tid] = mine; sred2[tid] = mine2;
        __syncthreads();
        for (int st = 128; st > 0; st >>= 1) {
            if (tid < st) { sred[tid] += sred[tid + st]; sred2[tid] += sred2[tid + st]; }
            __syncthreads();
        }
        if (tid == 0) { partials[NCB + s] = sred[0]; partials[NCB + 32 + s] = sred2[0]; }
    }
}

// Final combine: one 64-thread wave, shuffle-reduce in double.
__global__ void out_kernel(const double* __restrict__ partials,
                           float* __restrict__ out) {
    const int tid = threadIdx.x;   // 64 threads = 1 wave
    double t2 = 0.0, ce = 0.0, dx = 0.0;
    for (int i = tid; i < NCB; i += 64) t2 += partials[i];
    if (tid < 32) {
        ce = partials[NCB + tid];
        dx = partials[NCB + 32 + tid];
    }
#pragma unroll
    for (int off = 32; off > 0; off >>= 1) {
        t2 += __shfl_down(t2, off, 64);
        ce += __shfl_down(ce, off, 64);
        dx += __shfl_down(dx, off, 64);
    }
    if (tid == 0) {
        double ce_mean = ce / (double)B_DIM;
        double reg = -0.5 * (dx - t2) / ((double)C_DIM * (double)B_DIM);
        out[0] = (float)(ce_mean + reg);
    }
}

extern "C" void kernel_launch(void* const* d_in, const int* in_sizes, int n_in,
                              void* d_out, int out_size, void* d_ws, size_t ws_size,
                              hipStream_t stream) {
    const v4f* x4  = (const v4f*)d_in[0];
    const v4f* dm4 = (const v4f*)d_in[1];
    const int* target = (const int*)d_in[2];
    float* out = (float*)d_out;

    char* p = (char*)d_ws;
    auto alloc = [&](size_t bytes) {
        void* r = (void*)p;
        p += (bytes + 15) & ~(size_t)15;
        return r;
    };
    v4f*    colExpPart = (v4f*)alloc((size_t)NCHUNK * C4 * 16);
    v4f*    colDPart   = (v4f*)alloc((size_t)NCHUNK * C4 * 16);
    float*  rowPartExp = (float*)alloc((size_t)NT * B_DIM * 4);
    float*  rowPartDx  = (float*)alloc((size_t)NT * B_DIM * 4);
    float*  xt         = (float*)alloc((size_t)B_DIM * 4);
    double* partials   = (double*)alloc((NCB + 64) * 8);
    unsigned* perm     = (unsigned*)alloc((size_t)B_DIM * 4);

    sort_kernel<<<1, 1024, 0, stream>>>(target, perm);
    fused_main<<<dim3(NT, NCHUNK), 256, 0, stream>>>(
        x4, dm4, target, perm, colExpPart, colDPart, rowPartExp, rowPartDx, xt);
    fin2_kernel<<<NCB + 32, 256, 0, stream>>>(
        colExpPart, colDPart, rowPartExp, rowPartDx, xt, partials);
    out_kernel<<<1, 64, 0, stream>>>(partials, out);
}

// Round 10
// 120.066 us; speedup vs baseline: 1.7444x; 1.7444x over previous
//
#include <hip/hip_runtime.h>

#define B_DIM 8192
#define C_DIM 10000
#define C4    2500      // C_DIM / 4 (float4 groups)
#define NT    10        // column tiles of 256 float4 = 1024 columns
#define TILE4 256
#define NCHUNK 256      // row chunks -> grid 10x256 = 2560 blocks (8 resident/CU)
#define ROWCHUNK (B_DIM / NCHUNK)   // 32
#define NCB   157       // column blocks in fin2 (ceil(2500/16))

typedef float v4f __attribute__((ext_vector_type(4)));

// Fused main pass. Grid (NT, NCHUNK), block 256 (4 waves).
// Identical math to round 6; only the grid decomposition changed
// (ROWCHUNK 64->32) to raise occupancy from 20 to 32 waves/CU.
__global__ __launch_bounds__(256) void fused_main(
    const v4f* __restrict__ x4, const v4f* __restrict__ dm4,
    const int* __restrict__ target,
    v4f* __restrict__ colExpPart, v4f* __restrict__ colDPart,
    float* __restrict__ rowPartExp, float* __restrict__ rowPartDx,
    float* __restrict__ xt) {
    const int tile  = blockIdx.x;
    const int chunk = blockIdx.y;
    const int tid   = threadIdx.x;
    const int lane  = tid & 63;
    const int wave  = tid >> 6;
    const int base4 = tile * TILE4;
    const int row0  = chunk * ROWCHUNK;

    __shared__ int s_t[ROWCHUNK];
    __shared__ v4f sE[TILE4];
    __shared__ v4f sD[TILE4];

    for (int r = tid; r < ROWCHUNK; r += 256) s_t[r] = target[row0 + r];
    __syncthreads();

    int  col4[4];
    bool valid[4];
    v4f accE[4], accD[4];
#pragma unroll
    for (int it = 0; it < 4; ++it) {
        col4[it]  = base4 + it * 64 + lane;
        valid[it] = col4[it] < C4;
        accE[it] = (v4f){0.f, 0.f, 0.f, 0.f};
        accD[it] = (v4f){0.f, 0.f, 0.f, 0.f};
    }

    for (int r = wave; r < ROWCHUNK; r += 4) {
        const int row = row0 + r;
        const int t   = s_t[r];
        const v4f* xrow = x4 + (size_t)row * C4;
        const v4f* drow = dm4 + (size_t)t * C4;
        const int tq = t >> 2, tl = t & 3;
        float rowE = 0.f, rowDx = 0.f;
#pragma unroll
        for (int it = 0; it < 4; ++it) {
            if (!valid[it]) continue;
            // x is streamed exactly once: non-temporal (evict-first) so the
            // L2/L3 stay reserved for reused D rows.
            v4f xv = __builtin_nontemporal_load(&xrow[col4[it]]);
            v4f dv = drow[col4[it]];   // cached: D rows repeat across batch
            float ex = __expf(xv.x), ey = __expf(xv.y),
                  ez = __expf(xv.z), ew = __expf(xv.w);
            accE[it].x += ex; accE[it].y += ey; accE[it].z += ez; accE[it].w += ew;
            rowE += (ex + ey) + (ez + ew);
            accD[it].x += dv.x; accD[it].y += dv.y;
            accD[it].z += dv.z; accD[it].w += dv.w;
            rowDx += dv.x * xv.x + dv.y * xv.y + dv.z * xv.z + dv.w * xv.w;
            if (col4[it] == tq) {
                float v = (tl == 0) ? xv.x : (tl == 1) ? xv.y
                        : (tl == 2) ? xv.z : xv.w;
                xt[row] = v;
            }
        }
#pragma unroll
        for (int off = 32; off > 0; off >>= 1) {
            rowE  += __shfl_down(rowE, off, 64);
            rowDx += __shfl_down(rowDx, off, 64);
        }
        if (lane == 0) {
            rowPartExp[(size_t)tile * B_DIM + row] = rowE;
            rowPartDx [(size_t)tile * B_DIM + row] = rowDx;
        }
    }

    // Combine column partials across the 4 waves via LDS (deterministic).
    if (wave == 0) {
#pragma unroll
        for (int it = 0; it < 4; ++it) {
            sE[it * 64 + lane] = accE[it];
            sD[it * 64 + lane] = accD[it];
        }
    }
    __syncthreads();
    for (int w = 1; w < 4; ++w) {
        if (wave == w) {
#pragma unroll
            for (int it = 0; it < 4; ++it) {
                sE[it * 64 + lane] += accE[it];
                sD[it * 64 + lane] += accD[it];
            }
        }
        __syncthreads();
    }
    const int colg = base4 + tid;
    if (colg < C4) {
        colExpPart[(size_t)chunk * C4 + colg] = sE[tid];
        colDPart [(size_t)chunk * C4 + colg] = sD[tid];
    }
}

// Single merged finalize. Grid NCB+32 = 189 blocks x 256.
__global__ __launch_bounds__(256) void fin2_kernel(
    const v4f* __restrict__ colExpPart, const v4f* __restrict__ colDPart,
    const float* __restrict__ rowPartExp, const float* __restrict__ rowPartDx,
    const float* __restrict__ xt, double* __restrict__ partials) {
    const int b   = blockIdx.x;
    const int tid = threadIdx.x;
    __shared__ double sred[256];

    if (b < NCB) {
        const int cl   = tid & 15;
        const int q    = tid >> 4;           // 0..15
        const int col4 = b * 16 + cl;
        v4f se = {0.f, 0.f, 0.f, 0.f};
        v4f sd = {0.f, 0.f, 0.f, 0.f};
        if (col4 < C4) {
            for (int c = q; c < NCHUNK; c += 16) {
                se += __builtin_nontemporal_load(&colExpPart[(size_t)c * C4 + col4]);
                sd += __builtin_nontemporal_load(&colDPart [(size_t)c * C4 + col4]);
            }
        }
        __shared__ v4f lE[256], lD[256];
        lE[tid] = se; lD[tid] = sd;
        __syncthreads();
        for (int s = 8; s > 0; s >>= 1) {     // tree over q
            if (q < s) { lE[tid] += lE[tid + s * 16]; lD[tid] += lD[tid + s * 16]; }
            __syncthreads();
        }
        double mine = 0.0;
        if (q == 0 && col4 < C4) {
            v4f e = lE[tid];
            v4f d = lD[tid];
            mine = (double)d.x * (double)__logf(e.x)
                 + (double)d.y * (double)__logf(e.y)
                 + (double)d.z * (double)__logf(e.z)
                 + (double)d.w * (double)__logf(e.w);
        }
        sred[tid] = mine;
        __syncthreads();
        for (int s = 128; s > 0; s >>= 1) {
            if (tid < s) sred[tid] += sred[tid + s];
            __syncthreads();
        }
        if (tid == 0) partials[b] = sred[0];
    } else {
        const int s = b - NCB;
        const int i = s * 256 + tid;          // < 8192 exactly
        float re = 0.f, rdx = 0.f;
#pragma unroll
        for (int t = 0; t < NT; ++t) {
            re  += rowPartExp[(size_t)t * B_DIM + i];
            rdx += rowPartDx [(size_t)t * B_DIM + i];
        }
        double mine  = (double)(__logf(re) - xt[i]);
        double mine2 = (double)rdx;
        __shared__ double sred2[256];
        sred[tid] = mine; sred2[tid] = mine2;
        __syncthreads();
        for (int st = 128; st > 0; st >>= 1) {
            if (tid < st) { sred[tid] += sred[tid + st]; sred2[tid] += sred2[tid + st]; }
            __syncthreads();
        }
        if (tid == 0) { partials[NCB + s] = sred[0]; partials[NCB + 32 + s] = sred2[0]; }
    }
}

// Final combine: one 64-thread wave, shuffle-reduce in double.
__global__ void out_kernel(const double* __restrict__ partials,
                           float* __restrict__ out) {
    const int tid = threadIdx.x;   // 64 threads = 1 wave
    double t2 = 0.0, ce = 0.0, dx = 0.0;
    for (int i = tid; i < NCB; i += 64) t2 += partials[i];
    if (tid < 32) {
        ce = partials[NCB + tid];
        dx = partials[NCB + 32 + tid];
    }
#pragma unroll
    for (int off = 32; off > 0; off >>= 1) {
        t2 += __shfl_down(t2, off, 64);
        ce += __shfl_down(ce, off, 64);
        dx += __shfl_down(dx, off, 64);
    }
    if (tid == 0) {
        double ce_mean = ce / (double)B_DIM;
        double reg = -0.5 * (dx - t2) / ((double)C_DIM * (double)B_DIM);
        out[0] = (float)(ce_mean + reg);
    }
}

extern "C" void kernel_launch(void* const* d_in, const int* in_sizes, int n_in,
                              void* d_out, int out_size, void* d_ws, size_t ws_size,
                              hipStream_t stream) {
    const v4f* x4  = (const v4f*)d_in[0];
    const v4f* dm4 = (const v4f*)d_in[1];
    const int* target = (const int*)d_in[2];
    float* out = (float*)d_out;

    char* p = (char*)d_ws;
    auto alloc = [&](size_t bytes) {
        void* r = (void*)p;
        p += (bytes + 15) & ~(size_t)15;
        return r;
    };
    v4f*    colExpPart = (v4f*)alloc((size_t)NCHUNK * C4 * 16);
    v4f*    colDPart   = (v4f*)alloc((size_t)NCHUNK * C4 * 16);
    float*  rowPartExp = (float*)alloc((size_t)NT * B_DIM * 4);
    float*  rowPartDx  = (float*)alloc((size_t)NT * B_DIM * 4);
    float*  xt         = (float*)alloc((size_t)B_DIM * 4);
    double* partials   = (double*)alloc((NCB + 64) * 8);

    fused_main<<<dim3(NT, NCHUNK), 256, 0, stream>>>(
        x4, dm4, target, colExpPart, colDPart, rowPartExp, rowPartDx, xt);
    fin2_kernel<<<NCB + 32, 256, 0, stream>>>(
        colExpPart, colDPart, rowPartExp, rowPartDx, xt, partials);
    out_kernel<<<1, 64, 0, stream>>>(partials, out);
}

// Round 11
// 109.672 us; speedup vs baseline: 1.9097x; 1.0948x over previous
//
#include <hip/hip_runtime.h>

#define B_DIM 8192
#define C_DIM 10000
#define C4    2500      // C_DIM / 4 (float4 groups)
#define NT    10        // column tiles of 256 float4 = 1024 columns
#define TILE4 256
#define NCHUNK 128      // row chunks -> grid 10x128 = 1280 blocks = 5/CU exact
#define ROWCHUNK (B_DIM / NCHUNK)   // 64
#define NCB   157       // column blocks in fin2 (ceil(2500/16))

typedef float v4f __attribute__((ext_vector_type(4)));

// Fused main pass. Grid (NT, NCHUNK), block 256 (4 waves).
// Best measured configuration (round 6): 5 blocks/CU, x streamed nt,
// D rows L3-resident, ~663 MB delivered at the ~6.6 TB/s delivery ceiling.
__global__ __launch_bounds__(256) void fused_main(
    const v4f* __restrict__ x4, const v4f* __restrict__ dm4,
    const int* __restrict__ target,
    v4f* __restrict__ colExpPart, v4f* __restrict__ colDPart,
    float* __restrict__ rowPartExp, float* __restrict__ rowPartDx,
    float* __restrict__ xt) {
    const int tile  = blockIdx.x;
    const int chunk = blockIdx.y;
    const int tid   = threadIdx.x;
    const int lane  = tid & 63;
    const int wave  = tid >> 6;
    const int base4 = tile * TILE4;
    const int row0  = chunk * ROWCHUNK;

    __shared__ int s_t[ROWCHUNK];
    __shared__ v4f sE[TILE4];
    __shared__ v4f sD[TILE4];

    for (int r = tid; r < ROWCHUNK; r += 256) s_t[r] = target[row0 + r];
    __syncthreads();

    int  col4[4];
    bool valid[4];
    v4f accE[4], accD[4];
#pragma unroll
    for (int it = 0; it < 4; ++it) {
        col4[it]  = base4 + it * 64 + lane;
        valid[it] = col4[it] < C4;
        accE[it] = (v4f){0.f, 0.f, 0.f, 0.f};
        accD[it] = (v4f){0.f, 0.f, 0.f, 0.f};
    }

    for (int r = wave; r < ROWCHUNK; r += 4) {
        const int row = row0 + r;
        const int t   = s_t[r];
        const v4f* xrow = x4 + (size_t)row * C4;
        const v4f* drow = dm4 + (size_t)t * C4;
        const int tq = t >> 2, tl = t & 3;
        float rowE = 0.f, rowDx = 0.f;
#pragma unroll
        for (int it = 0; it < 4; ++it) {
            if (!valid[it]) continue;
            // x is streamed exactly once: non-temporal (evict-first) so the
            // L2/L3 stay reserved for reused D rows.
            v4f xv = __builtin_nontemporal_load(&xrow[col4[it]]);
            v4f dv = drow[col4[it]];   // cached: D rows repeat across batch
            float ex = __expf(xv.x), ey = __expf(xv.y),
                  ez = __expf(xv.z), ew = __expf(xv.w);
            accE[it].x += ex; accE[it].y += ey; accE[it].z += ez; accE[it].w += ew;
            rowE += (ex + ey) + (ez + ew);
            accD[it].x += dv.x; accD[it].y += dv.y;
            accD[it].z += dv.z; accD[it].w += dv.w;
            rowDx += dv.x * xv.x + dv.y * xv.y + dv.z * xv.z + dv.w * xv.w;
            if (col4[it] == tq) {
                float v = (tl == 0) ? xv.x : (tl == 1) ? xv.y
                        : (tl == 2) ? xv.z : xv.w;
                xt[row] = v;
            }
        }
#pragma unroll
        for (int off = 32; off > 0; off >>= 1) {
            rowE  += __shfl_down(rowE, off, 64);
            rowDx += __shfl_down(rowDx, off, 64);
        }
        if (lane == 0) {
            rowPartExp[(size_t)tile * B_DIM + row] = rowE;
            rowPartDx [(size_t)tile * B_DIM + row] = rowDx;
        }
    }

    // Combine column partials across the 4 waves via LDS (deterministic).
    if (wave == 0) {
#pragma unroll
        for (int it = 0; it < 4; ++it) {
            sE[it * 64 + lane] = accE[it];
            sD[it * 64 + lane] = accD[it];
        }
    }
    __syncthreads();
    for (int w = 1; w < 4; ++w) {
        if (wave == w) {
#pragma unroll
            for (int it = 0; it < 4; ++it) {
                sE[it * 64 + lane] += accE[it];
                sD[it * 64 + lane] += accD[it];
            }
        }
        __syncthreads();
    }
    const int colg = base4 + tid;
    if (colg < C4) {
        colExpPart[(size_t)chunk * C4 + colg] = sE[tid];
        colDPart [(size_t)chunk * C4 + colg] = sD[tid];
    }
}

// Single merged finalize. Grid NCB+32 = 189 blocks x 256.
__global__ __launch_bounds__(256) void fin2_kernel(
    const v4f* __restrict__ colExpPart, const v4f* __restrict__ colDPart,
    const float* __restrict__ rowPartExp, const float* __restrict__ rowPartDx,
    const float* __restrict__ xt, double* __restrict__ partials) {
    const int b   = blockIdx.x;
    const int tid = threadIdx.x;
    __shared__ double sred[256];

    if (b < NCB) {
        const int cl   = tid & 15;
        const int q    = tid >> 4;           // 0..15
        const int col4 = b * 16 + cl;
        v4f se = {0.f, 0.f, 0.f, 0.f};
        v4f sd = {0.f, 0.f, 0.f, 0.f};
        if (col4 < C4) {
            for (int c = q; c < NCHUNK; c += 16) {
                se += __builtin_nontemporal_load(&colExpPart[(size_t)c * C4 + col4]);
                sd += __builtin_nontemporal_load(&colDPart [(size_t)c * C4 + col4]);
            }
        }
        __shared__ v4f lE[256], lD[256];
        lE[tid] = se; lD[tid] = sd;
        __syncthreads();
        for (int s = 8; s > 0; s >>= 1) {     // tree over q
            if (q < s) { lE[tid] += lE[tid + s * 16]; lD[tid] += lD[tid + s * 16]; }
            __syncthreads();
        }
        double mine = 0.0;
        if (q == 0 && col4 < C4) {
            v4f e = lE[tid];
            v4f d = lD[tid];
            mine = (double)d.x * (double)__logf(e.x)
                 + (double)d.y * (double)__logf(e.y)
                 + (double)d.z * (double)__logf(e.z)
                 + (double)d.w * (double)__logf(e.w);
        }
        sred[tid] = mine;
        __syncthreads();
        for (int s = 128; s > 0; s >>= 1) {
            if (tid < s) sred[tid] += sred[tid + s];
            __syncthreads();
        }
        if (tid == 0) partials[b] = sred[0];
    } else {
        const int s = b - NCB;
        const int i = s * 256 + tid;          // < 8192 exactly
        float re = 0.f, rdx = 0.f;
#pragma unroll
        for (int t = 0; t < NT; ++t) {
            re  += rowPartExp[(size_t)t * B_DIM + i];
            rdx += rowPartDx [(size_t)t * B_DIM + i];
        }
        double mine  = (double)(__logf(re) - xt[i]);
        double mine2 = (double)rdx;
        __shared__ double sred2[256];
        sred[tid] = mine; sred2[tid] = mine2;
        __syncthreads();
        for (int st = 128; st > 0; st >>= 1) {
            if (tid < st) { sred[tid] += sred[tid + st]; sred2[tid] += sred2[tid + st]; }
            __syncthreads();
        }
        if (tid == 0) { partials[NCB + s] = sred[0]; partials[NCB + 32 + s] = sred2[0]; }
    }
}

// Final combine: one 64-thread wave, shuffle-reduce in double.
__global__ void out_kernel(const double* __restrict__ partials,
                           float* __restrict__ out) {
    const int tid = threadIdx.x;   // 64 threads = 1 wave
    double t2 = 0.0, ce = 0.0, dx = 0.0;
    for (int i = tid; i < NCB; i += 64) t2 += partials[i];
    if (tid < 32) {
        ce = partials[NCB + tid];
        dx = partials[NCB + 32 + tid];
    }
#pragma unroll
    for (int off = 32; off > 0; off >>= 1) {
        t2 += __shfl_down(t2, off, 64);
        ce += __shfl_down(ce, off, 64);
        dx += __shfl_down(dx, off, 64);
    }
    if (tid == 0) {
        double ce_mean = ce / (double)B_DIM;
        double reg = -0.5 * (dx - t2) / ((double)C_DIM * (double)B_DIM);
        out[0] = (float)(ce_mean + reg);
    }
}

extern "C" void kernel_launch(void* const* d_in, const int* in_sizes, int n_in,
                              void* d_out, int out_size, void* d_ws, size_t ws_size,
                              hipStream_t stream) {
    const v4f* x4  = (const v4f*)d_in[0];
    const v4f* dm4 = (const v4f*)d_in[1];
    const int* target = (const int*)d_in[2];
    float* out = (float*)d_out;

    char* p = (char*)d_ws;
    auto alloc = [&](size_t bytes) {
        void* r = (void*)p;
        p += (bytes + 15) & ~(size_t)15;
        return r;
    };
    v4f*    colExpPart = (v4f*)alloc((size_t)NCHUNK * C4 * 16);
    v4f*    colDPart   = (v4f*)alloc((size_t)NCHUNK * C4 * 16);
    float*  rowPartExp = (float*)alloc((size_t)NT * B_DIM * 4);
    float*  rowPartDx  = (float*)alloc((size_t)NT * B_DIM * 4);
    float*  xt         = (float*)alloc((size_t)B_DIM * 4);
    double* partials   = (double*)alloc((NCB + 64) * 8);

    fused_main<<<dim3(NT, NCHUNK), 256, 0, stream>>>(
        x4, dm4, target, colExpPart, colDPart, rowPartExp, rowPartDx, xt);
    fin2_kernel<<<NCB + 32, 256, 0, stream>>>(
        colExpPart, colDPart, rowPartExp, rowPartDx, xt, partials);
    out_kernel<<<1, 64, 0, stream>>>(partials, out);
}